// Round 12
// baseline (273.845 us; speedup 1.0000x reference)
//
#include <hip/hip_runtime.h>
#include <hip/hip_bf16.h>
#include <stdint.h>

#define B_ 4
#define C_ 16
#define P_ 512
#define D_ 256
#define H_ 8
#define SCALE 0.17677669529663687f   // 1/sqrt(32)
#define LOG2E 1.4426950408889634f
#define NE 8388608                    // B*C*P*D

typedef float4 f4;
typedef uint32_t u32;
typedef __attribute__((ext_vector_type(4))) float f32x4;
typedef __attribute__((ext_vector_type(8))) short short8;

__device__ __forceinline__ unsigned short bf16bits(float x) {
  union { __hip_bfloat16 h; unsigned short u; } cv;
  cv.h = __float2bfloat16(x);
  return cv.u;
}
__device__ __forceinline__ float bf2f(unsigned short u) {
  return __uint_as_float((u32)u << 16);
}
__device__ __forceinline__ u32 packbf2(float a, float b) {
  return ((u32)bf16bits(b) << 16) | bf16bits(a);
}
// native transcendentals via compiler intrinsics (hazard-safe, 1 instr each)
__device__ __forceinline__ float nexp2(float x) { return __builtin_amdgcn_exp2f(x); }
__device__ __forceinline__ float nrcp(float x)  { return __builtin_amdgcn_rcpf(x); }

// ---------------- prep: qz -> qzh/qzl (hi/lo bf16) + qzT (bf16, [bc][d][p]) ----------------
__global__ __launch_bounds__(256)
void prep_qz(const float* __restrict__ qz, ushort* __restrict__ qzh,
             ushort* __restrict__ qzl, ushort* __restrict__ qzT) {
  const int bc = blockIdx.y;
  const int pt = blockIdx.x >> 2, dt = blockIdx.x & 3;
  const int t = threadIdx.x;
  const int row = t >> 2, cq = t & 3;
  __shared__ float T[64][65];

  const int p = pt * 64 + row;
  const int d0 = dt * 64 + cq * 16;
  const size_t base = (size_t)bc * 131072 + (size_t)p * 256 + d0;
  float v[16];
#pragma unroll
  for (int i = 0; i < 4; ++i) {
    f4 x = *(const f4*)(qz + base + i * 4);
    v[i*4+0] = x.x; v[i*4+1] = x.y; v[i*4+2] = x.z; v[i*4+3] = x.w;
  }
  ushort hs[16], ls[16];
#pragma unroll
  for (int e = 0; e < 16; ++e) {
    unsigned short hb = bf16bits(v[e]);
    hs[e] = hb;
    ls[e] = bf16bits(v[e] - bf2f(hb));
    T[cq * 16 + e][row] = v[e];
  }
  *(ushort4*)(qzh + base)     = make_ushort4(hs[0],hs[1],hs[2],hs[3]);
  *(ushort4*)(qzh + base + 4) = make_ushort4(hs[4],hs[5],hs[6],hs[7]);
  *(ushort4*)(qzh + base + 8) = make_ushort4(hs[8],hs[9],hs[10],hs[11]);
  *(ushort4*)(qzh + base +12) = make_ushort4(hs[12],hs[13],hs[14],hs[15]);
  *(ushort4*)(qzl + base)     = make_ushort4(ls[0],ls[1],ls[2],ls[3]);
  *(ushort4*)(qzl + base + 4) = make_ushort4(ls[4],ls[5],ls[6],ls[7]);
  *(ushort4*)(qzl + base + 8) = make_ushort4(ls[8],ls[9],ls[10],ls[11]);
  *(ushort4*)(qzl + base +12) = make_ushort4(ls[12],ls[13],ls[14],ls[15]);
  __syncthreads();
  const int drow = t >> 2, pq = t & 3;
  ushort os[16];
#pragma unroll
  for (int e = 0; e < 16; ++e) os[e] = bf16bits(T[drow][pq * 16 + e]);
  const size_t tbase = (size_t)bc * 131072 + (size_t)(dt * 64 + drow) * 512 + pt * 64 + pq * 16;
  *(ushort4*)(qzT + tbase)     = make_ushort4(os[0],os[1],os[2],os[3]);
  *(ushort4*)(qzT + tbase + 4) = make_ushort4(os[4],os[5],os[6],os[7]);
  *(ushort4*)(qzT + tbase + 8) = make_ushort4(os[8],os[9],os[10],os[11]);
  *(ushort4*)(qzT + tbase +12) = make_ushort4(os[12],os[13],os[14],os[15]);
}

// ---------------- prep: weights -> concat [br][b][512][256] hi/lo bf16, U rows scaled by SCALE*LOG2E ----------------
__global__ __launch_bounds__(256)
void prep_w(const float* __restrict__ tu, const float* __restrict__ tv,
            const float* __restrict__ cu, const float* __restrict__ cv,
            ushort* __restrict__ wh, ushort* __restrict__ wl) {
  const int e4 = blockIdx.x * 256 + threadIdx.x;
  const int idx = e4 * 4;
  const int k0 = idx & 255;
  const int n  = (idx >> 8) & 511;
  const int b  = (idx >> 17) & 3;
  const int br = idx >> 19;
  const float* src;
  float sc;
  if (br == 0) {
    if (n < 256) { src = tu + ((size_t)b * 256 + n) * 256 + k0; sc = SCALE * LOG2E; }
    else         { src = tv + ((size_t)b * 256 + (n - 256)) * 256 + k0; sc = 1.f; }
  } else {
    if (n < 256) { src = cu + ((size_t)b * 256 + n) * 256 + k0; sc = SCALE * LOG2E; }
    else         { src = cv + ((size_t)b * 256 + (n - 256)) * 256 + k0; sc = 1.f; }
  }
  f4 x = *(const f4*)src;
  float v[4] = {x.x * sc, x.y * sc, x.z * sc, x.w * sc};
  ushort hs[4], ls[4];
#pragma unroll
  for (int e = 0; e < 4; ++e) {
    unsigned short hb = bf16bits(v[e]);
    hs[e] = hb;
    ls[e] = bf16bits(v[e] - bf2f(hb));
  }
  const size_t dst = ((size_t)(br * 4 + b) * 512 + n) * 256 + k0;
  *(ushort4*)(wh + dst) = make_ushort4(hs[0], hs[1], hs[2], hs[3]);
  *(ushort4*)(wl + dst) = make_ushort4(ls[0], ls[1], ls[2], ls[3]);
}

// ---------------- proj_all: MFMA GEMM, tile 128x128, K=256, 3-mfma hi/lo ----------------
// grid (m=64, nt=8, b=4). LDS-transpose epilogue -> wide coalesced stores.
__global__ __launch_bounds__(256, 2)
void proj_all(const ushort* __restrict__ qzh, const ushort* __restrict__ qzl,
              const ushort* __restrict__ wh, const ushort* __restrict__ wl,
              ushort* __restrict__ quh, ushort* __restrict__ qul,
              ushort* __restrict__ qvh, ushort* __restrict__ qvl,
              float* __restrict__ qcu, float* __restrict__ qcv) {
  __shared__ char smem[65536];
  const int b = blockIdx.z;
  const int m0 = blockIdx.x * 128;
  const int nt = blockIdx.y;
  const int br = nt >> 2;
  const int n0l = (nt & 3) * 128;
  const int tid = threadIdx.x;
  const int w = tid >> 6, lane = tid & 63;
  const int g = lane >> 4, li = lane & 15;
  const int wm = w >> 1, wn = w & 1;

  f32x4 acc[4][4];
#pragma unroll
  for (int i = 0; i < 4; ++i)
#pragma unroll
    for (int j = 0; j < 4; ++j) acc[i][j] = f32x4{0.f,0.f,0.f,0.f};

  auto stage = [&](int buf, int ks) {
#pragma unroll
    for (int i = 0; i < 4; ++i) {
      int cch = i * 256 + tid;
      int row = cch >> 3, col = cch & 7;
      const ushort* s = (col < 4 ? qzh : qzl) + (size_t)(b * 8192 + m0 + row) * 256 + ks * 32 + (col & 3) * 8;
      uint4 v = *(const uint4*)s;
      *(uint4*)(smem + buf * 16384 + row * 128 + ((col * 16) ^ ((row & 7) << 4))) = v;
    }
#pragma unroll
    for (int i = 0; i < 4; ++i) {
      int cch = i * 256 + tid;
      int row = cch >> 3, col = cch & 7;
      const ushort* s = (col < 4 ? wh : wl) + ((size_t)(br * 4 + b) * 512 + n0l + row) * 256 + ks * 32 + (col & 3) * 8;
      uint4 v = *(const uint4*)s;
      *(uint4*)(smem + 32768 + buf * 16384 + row * 128 + ((col * 16) ^ ((row & 7) << 4))) = v;
    }
  };

  stage(0, 0);
  __syncthreads();
  int buf = 0;
  for (int ks = 0; ks < 8; ++ks) {
    if (ks < 7) stage(buf ^ 1, ks + 1);
    const char* Ab = smem + buf * 16384;
    const char* Bb = smem + 32768 + buf * 16384;
    const int sw = (li & 7) << 4;
    short8 ah[4], al[4];
#pragma unroll
    for (int mt = 0; mt < 4; ++mt) {
      int r = (wm * 64 + mt * 16 + li) * 128;
      ah[mt] = *(const short8*)(Ab + r + ((g * 16) ^ sw));
      al[mt] = *(const short8*)(Ab + r + ((64 + g * 16) ^ sw));
    }
#pragma unroll
    for (int nt2 = 0; nt2 < 4; ++nt2) {
      int r = (wn * 64 + nt2 * 16 + li) * 128;
      short8 bh = *(const short8*)(Bb + r + ((g * 16) ^ sw));
      short8 bl = *(const short8*)(Bb + r + ((64 + g * 16) ^ sw));
#pragma unroll
      for (int mt = 0; mt < 4; ++mt) {
        acc[mt][nt2] = __builtin_amdgcn_mfma_f32_16x16x32_bf16(ah[mt], bh, acc[mt][nt2], 0, 0, 0);
        acc[mt][nt2] = __builtin_amdgcn_mfma_f32_16x16x32_bf16(ah[mt], bl, acc[mt][nt2], 0, 0, 0);
        acc[mt][nt2] = __builtin_amdgcn_mfma_f32_16x16x32_bf16(al[mt], bh, acc[mt][nt2], 0, 0, 0);
      }
    }
    __syncthreads();
    buf ^= 1;
  }

  // ---- epilogue: stage C-tile in LDS (XOR-swizzled), re-read row-wise, wide stores ----
  const int p_loc = tid >> 1;
  const int nh = (tid & 1) * 64;
  const int m = m0 + p_loc;
  const int cc = m >> 9, p = m & 511;
  if (br == 0) {
    u32* S = (u32*)smem;
#pragma unroll
    for (int mt = 0; mt < 4; ++mt)
#pragma unroll
      for (int nt2 = 0; nt2 < 4; ++nt2)
#pragma unroll
        for (int j = 0; j < 4; ++j) {
          int ml = wm * 64 + mt * 16 + g * 4 + j;
          int nl = wn * 64 + nt2 * 16 + li;
          float val = acc[mt][nt2][j];
          unsigned short hb = bf16bits(val);
          unsigned short lb = bf16bits(val - bf2f(hb));
          S[ml * 128 + (nl ^ ((ml & 7) << 2))] = ((u32)hb << 16) | lb;
        }
    __syncthreads();
    ushort* oh = (n0l < 256) ? quh : qvh;
    ushort* ol = (n0l < 256) ? qul : qvl;
    const int sx = (p_loc & 7) << 2;
#pragma unroll
    for (int c8 = 0; c8 < 8; ++c8) {
      int n0b = nh + c8 * 8;
      uint4 va = *(uint4*)&S[p_loc * 128 + (n0b ^ sx)];
      uint4 vb = *(uint4*)&S[p_loc * 128 + ((n0b + 4) ^ sx)];
      u32 u[8] = {va.x, va.y, va.z, va.w, vb.x, vb.y, vb.z, vb.w};
      short8 hsv, lsv;
#pragma unroll
      for (int e = 0; e < 8; ++e) {
        hsv[e] = (short)(u[e] >> 16);
        lsv[e] = (short)(u[e] & 0xffffu);
      }
      int nn = (n0l & 255) + n0b;
      int h = nn >> 5, r = nn & 31;
      size_t dst = ((((size_t)b * 16 + cc) * 8 + h) * 512 + p) * 32 + r;
      *(short8*)(oh + dst) = hsv;
      *(short8*)(ol + dst) = lsv;
    }
  } else {
    float* S = (float*)smem;
#pragma unroll
    for (int mt = 0; mt < 4; ++mt)
#pragma unroll
      for (int nt2 = 0; nt2 < 4; ++nt2)
#pragma unroll
        for (int j = 0; j < 4; ++j) {
          int ml = wm * 64 + mt * 16 + g * 4 + j;
          int nl = wn * 64 + nt2 * 16 + li;
          S[ml * 128 + (nl ^ ((ml & 7) << 2))] = acc[mt][nt2][j];
        }
    __syncthreads();
    float* oc = (n0l < 256) ? qcu : qcv;
    const int sx = (p_loc & 7) << 2;
#pragma unroll
    for (int i4 = 0; i4 < 16; ++i4) {
      f4 v = *(f4*)&S[p_loc * 128 + ((nh + i4 * 4) ^ sx)];
      int nn = (n0l & 255) + nh + i4 * 4;
      size_t dst = ((size_t)(b * 16 + cc) * 512 + p) * 256 + nn;
      *(f4*)(oc + dst) = v;
    }
  }
}

// ---------------- fused time attention v10: v8 structure + native exp/rcp (builtins) ----------------
// grid (bc=64, qt=32), block 256 (4 waves). Block owns 16 q-rows (q0+li); wave w owns
// keys [w*128,+128). Per lane: logits t[8] (32 regs), fp32 macc (32 regs). One 4-way
// (m,l) LDS exchange + barrier per head, exact merged rescale.
__global__ __launch_bounds__(256, 5)
void time_attn_v10(const ushort* __restrict__ quh, const ushort* __restrict__ qul,
                   const ushort* __restrict__ qvh, const ushort* __restrict__ qvl,
                   const ushort* __restrict__ qzT, float* __restrict__ out) {
  __shared__ char lds[17408];                // [16][1024B] probs tile + 1KB (m,l) exchange
  const int bc = blockIdx.x;
  const int q0 = blockIdx.y * 16;
  const int tid = threadIdx.x;
  const int w = tid >> 6, lane = tid & 63;
  const int g = lane >> 4, li = lane & 15;
  const int sw = (li & 7) << 4;
  float2* redml = (float2*)(lds + 16384);    // [2 buf][16 li][4 quarter]

  float macc[8][4];
#pragma unroll
  for (int kt = 0; kt < 8; ++kt)
#pragma unroll
    for (int j = 0; j < 4; ++j) macc[kt][j] = 0.f;

  int buf = 0;
#pragma unroll 1
  for (int h = 0; h < H_; ++h) {
    const size_t hb = (size_t)bc * 131072 + h * 16384;
    const size_t qoff = hb + (size_t)(q0 + li) * 32 + g * 8;
    short8 bh = *(const short8*)(quh + qoff);
    short8 bl = *(const short8*)(qul + qoff);
    const ushort* kh = qvh + hb + (size_t)(w * 128 + li) * 32 + g * 8;
    const ushort* kl = qvl + hb + (size_t)(w * 128 + li) * 32 + g * 8;

    // ---- single logit pass: 8 kt-tiles x 3 MFMA, logits in 32 regs ----
    f32x4 t[8];
#pragma unroll
    for (int kt = 0; kt < 8; ++kt) {
      short8 a_h = *(const short8*)(kh + kt * 512);
      short8 a_l = *(const short8*)(kl + kt * 512);
      f32x4 a = f32x4{0.f,0.f,0.f,0.f};
      a = __builtin_amdgcn_mfma_f32_16x16x32_bf16(a_h, bh, a, 0, 0, 0);
      a = __builtin_amdgcn_mfma_f32_16x16x32_bf16(a_h, bl, a, 0, 0, 0);
      a = __builtin_amdgcn_mfma_f32_16x16x32_bf16(a_l, bh, a, 0, 0, 0);
      t[kt] = a;
      if ((kt & 3) == 3) __builtin_amdgcn_sched_barrier(0);  // cap load hoisting
    }

    // ---- local (this quarter's 128 keys) max ----
    float m = -1e30f;
#pragma unroll
    for (int kt = 0; kt < 8; ++kt)
      m = fmaxf(m, fmaxf(fmaxf(t[kt][0], t[kt][1]), fmaxf(t[kt][2], t[kt][3])));
    m = fmaxf(m, __shfl_xor(m, 16));
    m = fmaxf(m, __shfl_xor(m, 32));

    // ---- native exp2 vs local max (in place) + local sum ----
    float l = 0.f;
#pragma unroll
    for (int kt = 0; kt < 8; ++kt) {
      float e0 = nexp2(t[kt][0] - m);
      float e1 = nexp2(t[kt][1] - m);
      float e2 = nexp2(t[kt][2] - m);
      float e3 = nexp2(t[kt][3] - m);
      t[kt][0] = e0; t[kt][1] = e1; t[kt][2] = e2; t[kt][3] = e3;
      l += (e0 + e1) + (e2 + e3);
    }
    l += __shfl_xor(l, 16);
    l += __shfl_xor(l, 32);

    // ---- one 4-way (m,l) exchange ----
    if (g == 0) redml[(buf * 16 + li) * 4 + w] = make_float2(m, l);
    __syncthreads();
    f4 r01 = ((const f4*)redml)[(buf * 16 + li) * 2 + 0];  // (m0,l0,m1,l1)
    f4 r23 = ((const f4*)redml)[(buf * 16 + li) * 2 + 1];  // (m2,l2,m3,l3)
    const float M = fmaxf(fmaxf(r01.x, r01.z), fmaxf(r23.x, r23.z));
    const float L = r01.y * nexp2(r01.x - M) + r01.w * nexp2(r01.z - M)
                  + r23.y * nexp2(r23.x - M) + r23.w * nexp2(r23.z - M);
    const float rinv = 0.125f * nexp2(m - M) * nrcp(L);

    // ---- merged-rescale accumulate into fp32 register macc ----
#pragma unroll
    for (int kt = 0; kt < 8; ++kt)
#pragma unroll
      for (int j = 0; j < 4; ++j)
        macc[kt][j] = fmaf(t[kt][j], rinv, macc[kt][j]);
    buf ^= 1;
  }

  // ---- head-mean probs -> bf16 LDS tile (once) ----
  {
    char* myrow = lds + li * 1024;
#pragma unroll
    for (int kt = 0; kt < 8; ++kt) {
      u32 p0 = packbf2(macc[kt][0], macc[kt][1]);
      u32 p1 = packbf2(macc[kt][2], macc[kt][3]);
      *(uint2*)(myrow + ((w * 256 + kt * 32 + g * 8) ^ sw)) = make_uint2(p0, p1);
    }
  }
  __syncthreads();

  // ---- PV: out[q][d] = probs[q][:] @ qzT[d][:]^T ; wave w -> d cols [w*64,+64) ----
  f32x4 oacc[4];
#pragma unroll
  for (int d = 0; d < 4; ++d) oacc[d] = f32x4{0.f,0.f,0.f,0.f};
  const ushort* qzTb = qzT + (size_t)bc * 131072;
#pragma unroll 2
  for (int ks = 0; ks < 16; ++ks) {
    short8 pa = *(const short8*)(lds + li * 1024 + ((ks * 64 + g * 16) ^ sw));
#pragma unroll
    for (int d = 0; d < 4; ++d) {
      short8 bz = *(const short8*)(qzTb + (size_t)((w * 4 + d) * 16 + li) * 512 + ks * 32 + g * 8);
      oacc[d] = __builtin_amdgcn_mfma_f32_16x16x32_bf16(pa, bz, oacc[d], 0, 0, 0);
    }
  }
  float* outB = out + (size_t)bc * 131072;
#pragma unroll
  for (int d = 0; d < 4; ++d)
#pragma unroll
    for (int j = 0; j < 4; ++j)
      outB[(size_t)(q0 + g * 4 + j) * 256 + w * 64 + d * 16 + li] = oacc[d][j];
}

// ---------------- fused channel attention (U pre-scaled by SCALE*LOG2E -> native exp2) ----------------
__global__ __launch_bounds__(64)
void chan_attn_kernel(const float* __restrict__ qu, const float* __restrict__ qv,
                      const float* __restrict__ qz, float* __restrict__ out) {
  const int p = blockIdx.x, b = blockIdx.y;
  __shared__ float buf0[16][260];
  __shared__ float qvC[16][260];
  __shared__ float A_m[16][17];

  const int tid = threadIdx.x;
  const int f = tid & 15;
  const int gg = tid >> 4;

#pragma unroll
  for (int cc = 0; cc < 16; ++cc) {
    size_t off = (((size_t)b * C_ + cc) * P_ + p) * D_ + tid*4;
    *(f4*)&buf0[cc][tid*4] = *(const f4*)&qu[off];
    *(f4*)&qvC[cc][tid*4]  = *(const f4*)&qv[off];
  }
  __syncthreads();

  float am[4] = {0.f, 0.f, 0.f, 0.f};
  for (int h = 0; h < H_; ++h) {
    f4 vr[8];
#pragma unroll
    for (int i = 0; i < 8; ++i) vr[i] = *(const f4*)&qvC[f][h*32 + i*4];
    float sj[4];
#pragma unroll
    for (int j = 0; j < 4; ++j) {
      int cc = gg + 4*j;
      float ssum = 0.f;
#pragma unroll
      for (int i = 0; i < 8; ++i) {
        f4 uu = *(const f4*)&buf0[cc][h*32 + i*4];
        ssum += uu.x*vr[i].x + uu.y*vr[i].y + uu.z*vr[i].z + uu.w*vr[i].w;
      }
      sj[j] = ssum;
    }
#pragma unroll
    for (int j = 0; j < 4; ++j) {
      float mx = sj[j];
      for (int off = 8; off >= 1; off >>= 1) mx = fmaxf(mx, __shfl_xor(mx, off));
      float pv = nexp2(sj[j] - mx);
      float sum = pv;
      for (int off = 8; off >= 1; off >>= 1) sum += __shfl_xor(sum, off);
      am[j] += pv * 0.125f * nrcp(sum);
    }
  }
#pragma unroll
  for (int j = 0; j < 4; ++j) A_m[gg + 4*j][f] = am[j];
  __syncthreads();
#pragma unroll
  for (int cc = 0; cc < 16; ++cc) {
    size_t off = (((size_t)b * C_ + cc) * P_ + p) * D_ + tid*4;
    *(f4*)&buf0[cc][tid*4] = *(const f4*)&qz[off];
  }
  __syncthreads();

  f4 acc4[16];
#pragma unroll
  for (int cc = 0; cc < 16; ++cc) acc4[cc] = make_float4(0.f, 0.f, 0.f, 0.f);
#pragma unroll
  for (int ff = 0; ff < 16; ++ff) {
    f4 z = *(const f4*)&buf0[ff][tid*4];
#pragma unroll
    for (int cc = 0; cc < 16; ++cc) {
      float aa = A_m[cc][ff];
      acc4[cc].x = fmaf(aa, z.x, acc4[cc].x);
      acc4[cc].y = fmaf(aa, z.y, acc4[cc].y);
      acc4[cc].z = fmaf(aa, z.z, acc4[cc].z);
      acc4[cc].w = fmaf(aa, z.w, acc4[cc].w);
    }
  }
#pragma unroll
  for (int cc = 0; cc < 16; ++cc) {
    size_t off = (((size_t)b * C_ + cc) * P_ + p) * D_ + tid*4;
    *(f4*)&out[off] = acc4[cc];
  }
}

extern "C" void kernel_launch(void* const* d_in, const int* in_sizes, int n_in,
                              void* d_out, int out_size, void* d_ws, size_t ws_size,
                              hipStream_t stream) {
  const float* qz = (const float*)d_in[0];
  const float* tu = (const float*)d_in[1];
  const float* tv = (const float*)d_in[2];
  const float* cu = (const float*)d_in[3];
  const float* cv = (const float*)d_in[4];
  float* out_mt = (float*)d_out;
  float* out_mc = out_mt + (size_t)NE;

  ushort* W = (ushort*)d_ws;
  ushort* qzh = W;
  ushort* qzl = qzh + NE;
  ushort* qzT = qzl + NE;
  ushort* wh  = qzT + NE;
  ushort* wl  = wh + 1048576;
  ushort* quh = wl + 1048576;
  ushort* qul = quh + NE;
  ushort* qvh = qul + NE;
  ushort* qvl = qvh + NE;
  float* qcu = out_mt;
  float* qcv = out_mc;

  hipLaunchKernelGGL(prep_qz, dim3(32, 64), dim3(256), 0, stream, qz, qzh, qzl, qzT);
  hipLaunchKernelGGL(prep_w, dim3(1024), dim3(256), 0, stream, tu, tv, cu, cv, wh, wl);
  hipLaunchKernelGGL(proj_all, dim3(64, 8, 4), dim3(256), 0, stream,
                     qzh, qzl, wh, wl, quh, qul, qvh, qvl, qcu, qcv);
  hipLaunchKernelGGL(chan_attn_kernel, dim3(P_, B_), dim3(64), 0, stream,
                     qcu, qcv, qz, out_mc);
  hipLaunchKernelGGL(time_attn_v10, dim3(64, 32), dim3(256), 0, stream,
                     quh, qul, qvh, qvl, qzT, out_mt);
}

// Round 19
// 250.940 us; speedup vs baseline: 1.0913x; 1.0913x over previous
//
#include <hip/hip_runtime.h>
#include <hip/hip_bf16.h>
#include <stdint.h>

#define B_ 4
#define C_ 16
#define P_ 512
#define D_ 256
#define H_ 8
#define SCALE 0.17677669529663687f   // 1/sqrt(32)
#define LOG2E 1.4426950408889634f
#define NE 8388608                    // B*C*P*D

typedef float4 f4;
typedef uint32_t u32;
typedef __attribute__((ext_vector_type(4))) float f32x4;
typedef __attribute__((ext_vector_type(8))) short short8;

__device__ __forceinline__ unsigned short bf16bits(float x) {
  union { __hip_bfloat16 h; unsigned short u; } cv;
  cv.h = __float2bfloat16(x);
  return cv.u;
}
__device__ __forceinline__ float bf2f(unsigned short u) {
  return __uint_as_float((u32)u << 16);
}
__device__ __forceinline__ u32 packbf2(float a, float b) {
  return ((u32)bf16bits(b) << 16) | bf16bits(a);
}
// native transcendentals via compiler intrinsics (hazard-safe, 1 instr each)
__device__ __forceinline__ float nexp2(float x) { return __builtin_amdgcn_exp2f(x); }
__device__ __forceinline__ float nrcp(float x)  { return __builtin_amdgcn_rcpf(x); }

// ---------------- prep: qz -> qzh/qzl (hi/lo bf16) + qzT (bf16, [bc][d][p]) ----------------
__global__ __launch_bounds__(256)
void prep_qz(const float* __restrict__ qz, ushort* __restrict__ qzh,
             ushort* __restrict__ qzl, ushort* __restrict__ qzT) {
  const int bc = blockIdx.y;
  const int pt = blockIdx.x >> 2, dt = blockIdx.x & 3;
  const int t = threadIdx.x;
  const int row = t >> 2, cq = t & 3;
  __shared__ float T[64][65];

  const int p = pt * 64 + row;
  const int d0 = dt * 64 + cq * 16;
  const size_t base = (size_t)bc * 131072 + (size_t)p * 256 + d0;
  float v[16];
#pragma unroll
  for (int i = 0; i < 4; ++i) {
    f4 x = *(const f4*)(qz + base + i * 4);
    v[i*4+0] = x.x; v[i*4+1] = x.y; v[i*4+2] = x.z; v[i*4+3] = x.w;
  }
  ushort hs[16], ls[16];
#pragma unroll
  for (int e = 0; e < 16; ++e) {
    unsigned short hb = bf16bits(v[e]);
    hs[e] = hb;
    ls[e] = bf16bits(v[e] - bf2f(hb));
    T[cq * 16 + e][row] = v[e];
  }
  *(ushort4*)(qzh + base)     = make_ushort4(hs[0],hs[1],hs[2],hs[3]);
  *(ushort4*)(qzh + base + 4) = make_ushort4(hs[4],hs[5],hs[6],hs[7]);
  *(ushort4*)(qzh + base + 8) = make_ushort4(hs[8],hs[9],hs[10],hs[11]);
  *(ushort4*)(qzh + base +12) = make_ushort4(hs[12],hs[13],hs[14],hs[15]);
  *(ushort4*)(qzl + base)     = make_ushort4(ls[0],ls[1],ls[2],ls[3]);
  *(ushort4*)(qzl + base + 4) = make_ushort4(ls[4],ls[5],ls[6],ls[7]);
  *(ushort4*)(qzl + base + 8) = make_ushort4(ls[8],ls[9],ls[10],ls[11]);
  *(ushort4*)(qzl + base +12) = make_ushort4(ls[12],ls[13],ls[14],ls[15]);
  __syncthreads();
  const int drow = t >> 2, pq = t & 3;
  ushort os[16];
#pragma unroll
  for (int e = 0; e < 16; ++e) os[e] = bf16bits(T[drow][pq * 16 + e]);
  const size_t tbase = (size_t)bc * 131072 + (size_t)(dt * 64 + drow) * 512 + pt * 64 + pq * 16;
  *(ushort4*)(qzT + tbase)     = make_ushort4(os[0],os[1],os[2],os[3]);
  *(ushort4*)(qzT + tbase + 4) = make_ushort4(os[4],os[5],os[6],os[7]);
  *(ushort4*)(qzT + tbase + 8) = make_ushort4(os[8],os[9],os[10],os[11]);
  *(ushort4*)(qzT + tbase +12) = make_ushort4(os[12],os[13],os[14],os[15]);
}

// ---------------- prep: weights -> concat [br][b][512][256] hi/lo bf16, U rows scaled by SCALE*LOG2E ----------------
__global__ __launch_bounds__(256)
void prep_w(const float* __restrict__ tu, const float* __restrict__ tv,
            const float* __restrict__ cu, const float* __restrict__ cv,
            ushort* __restrict__ wh, ushort* __restrict__ wl) {
  const int e4 = blockIdx.x * 256 + threadIdx.x;
  const int idx = e4 * 4;
  const int k0 = idx & 255;
  const int n  = (idx >> 8) & 511;
  const int b  = (idx >> 17) & 3;
  const int br = idx >> 19;
  const float* src;
  float sc;
  if (br == 0) {
    if (n < 256) { src = tu + ((size_t)b * 256 + n) * 256 + k0; sc = SCALE * LOG2E; }
    else         { src = tv + ((size_t)b * 256 + (n - 256)) * 256 + k0; sc = 1.f; }
  } else {
    if (n < 256) { src = cu + ((size_t)b * 256 + n) * 256 + k0; sc = SCALE * LOG2E; }
    else         { src = cv + ((size_t)b * 256 + (n - 256)) * 256 + k0; sc = 1.f; }
  }
  f4 x = *(const f4*)src;
  float v[4] = {x.x * sc, x.y * sc, x.z * sc, x.w * sc};
  ushort hs[4], ls[4];
#pragma unroll
  for (int e = 0; e < 4; ++e) {
    unsigned short hb = bf16bits(v[e]);
    hs[e] = hb;
    ls[e] = bf16bits(v[e] - bf2f(hb));
  }
  const size_t dst = ((size_t)(br * 4 + b) * 512 + n) * 256 + k0;
  *(ushort4*)(wh + dst) = make_ushort4(hs[0], hs[1], hs[2], hs[3]);
  *(ushort4*)(wl + dst) = make_ushort4(ls[0], ls[1], ls[2], ls[3]);
}

// ---------------- proj_all: MFMA GEMM, tile 128x128, K=256, 3-mfma hi/lo ----------------
// grid (m=64, nt=8, b=4). MFMA operands SWAPPED (A=W, B=qz) so each thread owns 4
// consecutive n-columns per fragment -> direct ushort4/float4 stores, no LDS epilogue.
__global__ __launch_bounds__(256, 2)
void proj_all(const ushort* __restrict__ qzh, const ushort* __restrict__ qzl,
              const ushort* __restrict__ wh, const ushort* __restrict__ wl,
              ushort* __restrict__ quh, ushort* __restrict__ qul,
              ushort* __restrict__ qvh, ushort* __restrict__ qvl,
              float* __restrict__ qcu, float* __restrict__ qcv) {
  __shared__ char smem[65536];
  const int b = blockIdx.z;
  const int m0 = blockIdx.x * 128;
  const int nt = blockIdx.y;
  const int br = nt >> 2;
  const int n0l = (nt & 3) * 128;
  const int tid = threadIdx.x;
  const int w = tid >> 6, lane = tid & 63;
  const int g = lane >> 4, li = lane & 15;
  const int wm = w >> 1, wn = w & 1;

  f32x4 acc[4][4];
#pragma unroll
  for (int i = 0; i < 4; ++i)
#pragma unroll
    for (int j = 0; j < 4; ++j) acc[i][j] = f32x4{0.f,0.f,0.f,0.f};

  auto stage = [&](int buf, int ks) {
#pragma unroll
    for (int i = 0; i < 4; ++i) {
      int cch = i * 256 + tid;
      int row = cch >> 3, col = cch & 7;
      const ushort* s = (col < 4 ? qzh : qzl) + (size_t)(b * 8192 + m0 + row) * 256 + ks * 32 + (col & 3) * 8;
      uint4 v = *(const uint4*)s;
      *(uint4*)(smem + buf * 16384 + row * 128 + ((col * 16) ^ ((row & 7) << 4))) = v;
    }
#pragma unroll
    for (int i = 0; i < 4; ++i) {
      int cch = i * 256 + tid;
      int row = cch >> 3, col = cch & 7;
      const ushort* s = (col < 4 ? wh : wl) + ((size_t)(br * 4 + b) * 512 + n0l + row) * 256 + ks * 32 + (col & 3) * 8;
      uint4 v = *(const uint4*)s;
      *(uint4*)(smem + 32768 + buf * 16384 + row * 128 + ((col * 16) ^ ((row & 7) << 4))) = v;
    }
  };

  stage(0, 0);
  __syncthreads();
  int buf = 0;
  for (int ks = 0; ks < 8; ++ks) {
    if (ks < 7) stage(buf ^ 1, ks + 1);
    const char* Ab = smem + buf * 16384;
    const char* Bb = smem + 32768 + buf * 16384;
    const int sw = (li & 7) << 4;
    short8 ah[4], al[4];
#pragma unroll
    for (int mt = 0; mt < 4; ++mt) {
      int r = (wm * 64 + mt * 16 + li) * 128;
      ah[mt] = *(const short8*)(Ab + r + ((g * 16) ^ sw));
      al[mt] = *(const short8*)(Ab + r + ((64 + g * 16) ^ sw));
    }
#pragma unroll
    for (int nt2 = 0; nt2 < 4; ++nt2) {
      int r = (wn * 64 + nt2 * 16 + li) * 128;
      short8 bh = *(const short8*)(Bb + r + ((g * 16) ^ sw));
      short8 bl = *(const short8*)(Bb + r + ((64 + g * 16) ^ sw));
#pragma unroll
      for (int mt = 0; mt < 4; ++mt) {
        // swapped operand order: D[n][m] -> thread owns 4 consecutive n for one m
        acc[mt][nt2] = __builtin_amdgcn_mfma_f32_16x16x32_bf16(bh, ah[mt], acc[mt][nt2], 0, 0, 0);
        acc[mt][nt2] = __builtin_amdgcn_mfma_f32_16x16x32_bf16(bh, al[mt], acc[mt][nt2], 0, 0, 0);
        acc[mt][nt2] = __builtin_amdgcn_mfma_f32_16x16x32_bf16(bl, ah[mt], acc[mt][nt2], 0, 0, 0);
      }
    }
    __syncthreads();
    buf ^= 1;
  }

  // ---- epilogue: per thread (mt,nt2) -> m = ..+li (one row), n = ..+g*4+j (4 consecutive) ----
  if (br == 0) {
    ushort* oh = (n0l < 256) ? quh : qvh;
    ushort* ol = (n0l < 256) ? qul : qvl;
#pragma unroll
    for (int mt = 0; mt < 4; ++mt) {
      int m = m0 + wm * 64 + mt * 16 + li;
      int cc = m >> 9, p = m & 511;
#pragma unroll
      for (int nt2 = 0; nt2 < 4; ++nt2) {
        int nn = (n0l & 255) + wn * 64 + nt2 * 16 + g * 4;
        ushort hsv[4], lsv[4];
#pragma unroll
        for (int j = 0; j < 4; ++j) {
          float val = acc[mt][nt2][j];
          unsigned short hb = bf16bits(val);
          hsv[j] = hb;
          lsv[j] = bf16bits(val - bf2f(hb));
        }
        int h = nn >> 5, r = nn & 31;
        size_t dst = ((((size_t)b * 16 + cc) * 8 + h) * 512 + p) * 32 + r;
        *(ushort4*)(oh + dst) = make_ushort4(hsv[0], hsv[1], hsv[2], hsv[3]);
        *(ushort4*)(ol + dst) = make_ushort4(lsv[0], lsv[1], lsv[2], lsv[3]);
      }
    }
  } else {
    float* oc = (n0l < 256) ? qcu : qcv;
#pragma unroll
    for (int mt = 0; mt < 4; ++mt) {
      int m = m0 + wm * 64 + mt * 16 + li;
      int cc = m >> 9, p = m & 511;
#pragma unroll
      for (int nt2 = 0; nt2 < 4; ++nt2) {
        int nn = (n0l & 255) + wn * 64 + nt2 * 16 + g * 4;
        size_t dst = ((size_t)(b * 16 + cc) * 512 + p) * 256 + nn;
        *(f4*)(oc + dst) = make_float4(acc[mt][nt2][0], acc[mt][nt2][1],
                                       acc[mt][nt2][2], acc[mt][nt2][3]);
      }
    }
  }
}

// ---------------- fused time attention v10: v8 structure + native exp/rcp (builtins) ----------------
// grid (bc=64, qt=32), block 256 (4 waves). Block owns 16 q-rows (q0+li); wave w owns
// keys [w*128,+128). Per lane: logits t[8] (32 regs), fp32 macc (32 regs). One 4-way
// (m,l) LDS exchange + barrier per head, exact merged rescale.
__global__ __launch_bounds__(256, 5)
void time_attn_v10(const ushort* __restrict__ quh, const ushort* __restrict__ qul,
                   const ushort* __restrict__ qvh, const ushort* __restrict__ qvl,
                   const ushort* __restrict__ qzT, float* __restrict__ out) {
  __shared__ char lds[17408];                // [16][1024B] probs tile + 1KB (m,l) exchange
  const int bc = blockIdx.x;
  const int q0 = blockIdx.y * 16;
  const int tid = threadIdx.x;
  const int w = tid >> 6, lane = tid & 63;
  const int g = lane >> 4, li = lane & 15;
  const int sw = (li & 7) << 4;
  float2* redml = (float2*)(lds + 16384);    // [2 buf][16 li][4 quarter]

  float macc[8][4];
#pragma unroll
  for (int kt = 0; kt < 8; ++kt)
#pragma unroll
    for (int j = 0; j < 4; ++j) macc[kt][j] = 0.f;

  int buf = 0;
#pragma unroll 1
  for (int h = 0; h < H_; ++h) {
    const size_t hb = (size_t)bc * 131072 + h * 16384;
    const size_t qoff = hb + (size_t)(q0 + li) * 32 + g * 8;
    short8 bh = *(const short8*)(quh + qoff);
    short8 bl = *(const short8*)(qul + qoff);
    const ushort* kh = qvh + hb + (size_t)(w * 128 + li) * 32 + g * 8;
    const ushort* kl = qvl + hb + (size_t)(w * 128 + li) * 32 + g * 8;

    // ---- single logit pass: 8 kt-tiles x 3 MFMA, logits in 32 regs ----
    f32x4 t[8];
#pragma unroll
    for (int kt = 0; kt < 8; ++kt) {
      short8 a_h = *(const short8*)(kh + kt * 512);
      short8 a_l = *(const short8*)(kl + kt * 512);
      f32x4 a = f32x4{0.f,0.f,0.f,0.f};
      a = __builtin_amdgcn_mfma_f32_16x16x32_bf16(a_h, bh, a, 0, 0, 0);
      a = __builtin_amdgcn_mfma_f32_16x16x32_bf16(a_h, bl, a, 0, 0, 0);
      a = __builtin_amdgcn_mfma_f32_16x16x32_bf16(a_l, bh, a, 0, 0, 0);
      t[kt] = a;
      if ((kt & 3) == 3) __builtin_amdgcn_sched_barrier(0);  // cap load hoisting
    }

    // ---- local (this quarter's 128 keys) max ----
    float m = -1e30f;
#pragma unroll
    for (int kt = 0; kt < 8; ++kt)
      m = fmaxf(m, fmaxf(fmaxf(t[kt][0], t[kt][1]), fmaxf(t[kt][2], t[kt][3])));
    m = fmaxf(m, __shfl_xor(m, 16));
    m = fmaxf(m, __shfl_xor(m, 32));

    // ---- native exp2 vs local max (in place) + local sum ----
    float l = 0.f;
#pragma unroll
    for (int kt = 0; kt < 8; ++kt) {
      float e0 = nexp2(t[kt][0] - m);
      float e1 = nexp2(t[kt][1] - m);
      float e2 = nexp2(t[kt][2] - m);
      float e3 = nexp2(t[kt][3] - m);
      t[kt][0] = e0; t[kt][1] = e1; t[kt][2] = e2; t[kt][3] = e3;
      l += (e0 + e1) + (e2 + e3);
    }
    l += __shfl_xor(l, 16);
    l += __shfl_xor(l, 32);

    // ---- one 4-way (m,l) exchange ----
    if (g == 0) redml[(buf * 16 + li) * 4 + w] = make_float2(m, l);
    __syncthreads();
    f4 r01 = ((const f4*)redml)[(buf * 16 + li) * 2 + 0];  // (m0,l0,m1,l1)
    f4 r23 = ((const f4*)redml)[(buf * 16 + li) * 2 + 1];  // (m2,l2,m3,l3)
    const float M = fmaxf(fmaxf(r01.x, r01.z), fmaxf(r23.x, r23.z));
    const float L = r01.y * nexp2(r01.x - M) + r01.w * nexp2(r01.z - M)
                  + r23.y * nexp2(r23.x - M) + r23.w * nexp2(r23.z - M);
    const float rinv = 0.125f * nexp2(m - M) * nrcp(L);

    // ---- merged-rescale accumulate into fp32 register macc ----
#pragma unroll
    for (int kt = 0; kt < 8; ++kt)
#pragma unroll
      for (int j = 0; j < 4; ++j)
        macc[kt][j] = fmaf(t[kt][j], rinv, macc[kt][j]);
    buf ^= 1;
  }

  // ---- head-mean probs -> bf16 LDS tile (once) ----
  {
    char* myrow = lds + li * 1024;
#pragma unroll
    for (int kt = 0; kt < 8; ++kt) {
      u32 p0 = packbf2(macc[kt][0], macc[kt][1]);
      u32 p1 = packbf2(macc[kt][2], macc[kt][3]);
      *(uint2*)(myrow + ((w * 256 + kt * 32 + g * 8) ^ sw)) = make_uint2(p0, p1);
    }
  }
  __syncthreads();

  // ---- PV: out[q][d] = probs[q][:] @ qzT[d][:]^T ; wave w -> d cols [w*64,+64) ----
  f32x4 oacc[4];
#pragma unroll
  for (int d = 0; d < 4; ++d) oacc[d] = f32x4{0.f,0.f,0.f,0.f};
  const ushort* qzTb = qzT + (size_t)bc * 131072;
#pragma unroll 2
  for (int ks = 0; ks < 16; ++ks) {
    short8 pa = *(const short8*)(lds + li * 1024 + ((ks * 64 + g * 16) ^ sw));
#pragma unroll
    for (int d = 0; d < 4; ++d) {
      short8 bz = *(const short8*)(qzTb + (size_t)((w * 4 + d) * 16 + li) * 512 + ks * 32 + g * 8);
      oacc[d] = __builtin_amdgcn_mfma_f32_16x16x32_bf16(pa, bz, oacc[d], 0, 0, 0);
    }
  }
  float* outB = out + (size_t)bc * 131072;
#pragma unroll
  for (int d = 0; d < 4; ++d)
#pragma unroll
    for (int j = 0; j < 4; ++j)
      outB[(size_t)(q0 + g * 4 + j) * 256 + w * 64 + d * 16 + li] = oacc[d][j];
}

// ---------------- fused channel attention (U pre-scaled by SCALE*LOG2E -> native exp2) ----------------
__global__ __launch_bounds__(64)
void chan_attn_kernel(const float* __restrict__ qu, const float* __restrict__ qv,
                      const float* __restrict__ qz, float* __restrict__ out) {
  const int p = blockIdx.x, b = blockIdx.y;
  __shared__ float buf0[16][260];
  __shared__ float qvC[16][260];
  __shared__ float A_m[16][17];

  const int tid = threadIdx.x;
  const int f = tid & 15;
  const int gg = tid >> 4;

#pragma unroll
  for (int cc = 0; cc < 16; ++cc) {
    size_t off = (((size_t)b * C_ + cc) * P_ + p) * D_ + tid*4;
    *(f4*)&buf0[cc][tid*4] = *(const f4*)&qu[off];
    *(f4*)&qvC[cc][tid*4]  = *(const f4*)&qv[off];
  }
  __syncthreads();

  float am[4] = {0.f, 0.f, 0.f, 0.f};
  for (int h = 0; h < H_; ++h) {
    f4 vr[8];
#pragma unroll
    for (int i = 0; i < 8; ++i) vr[i] = *(const f4*)&qvC[f][h*32 + i*4];
    float sj[4];
#pragma unroll
    for (int j = 0; j < 4; ++j) {
      int cc = gg + 4*j;
      float ssum = 0.f;
#pragma unroll
      for (int i = 0; i < 8; ++i) {
        f4 uu = *(const f4*)&buf0[cc][h*32 + i*4];
        ssum += uu.x*vr[i].x + uu.y*vr[i].y + uu.z*vr[i].z + uu.w*vr[i].w;
      }
      sj[j] = ssum;
    }
#pragma unroll
    for (int j = 0; j < 4; ++j) {
      float mx = sj[j];
      for (int off = 8; off >= 1; off >>= 1) mx = fmaxf(mx, __shfl_xor(mx, off));
      float pv = nexp2(sj[j] - mx);
      float sum = pv;
      for (int off = 8; off >= 1; off >>= 1) sum += __shfl_xor(sum, off);
      am[j] += pv * 0.125f * nrcp(sum);
    }
  }
#pragma unroll
  for (int j = 0; j < 4; ++j) A_m[gg + 4*j][f] = am[j];
  __syncthreads();
#pragma unroll
  for (int cc = 0; cc < 16; ++cc) {
    size_t off = (((size_t)b * C_ + cc) * P_ + p) * D_ + tid*4;
    *(f4*)&buf0[cc][tid*4] = *(const f4*)&qz[off];
  }
  __syncthreads();

  f4 acc4[16];
#pragma unroll
  for (int cc = 0; cc < 16; ++cc) acc4[cc] = make_float4(0.f, 0.f, 0.f, 0.f);
#pragma unroll
  for (int ff = 0; ff < 16; ++ff) {
    f4 z = *(const f4*)&buf0[ff][tid*4];
#pragma unroll
    for (int cc = 0; cc < 16; ++cc) {
      float aa = A_m[cc][ff];
      acc4[cc].x = fmaf(aa, z.x, acc4[cc].x);
      acc4[cc].y = fmaf(aa, z.y, acc4[cc].y);
      acc4[cc].z = fmaf(aa, z.z, acc4[cc].z);
      acc4[cc].w = fmaf(aa, z.w, acc4[cc].w);
    }
  }
#pragma unroll
  for (int cc = 0; cc < 16; ++cc) {
    size_t off = (((size_t)b * C_ + cc) * P_ + p) * D_ + tid*4;
    *(f4*)&out[off] = acc4[cc];
  }
}

extern "C" void kernel_launch(void* const* d_in, const int* in_sizes, int n_in,
                              void* d_out, int out_size, void* d_ws, size_t ws_size,
                              hipStream_t stream) {
  const float* qz = (const float*)d_in[0];
  const float* tu = (const float*)d_in[1];
  const float* tv = (const float*)d_in[2];
  const float* cu = (const float*)d_in[3];
  const float* cv = (const float*)d_in[4];
  float* out_mt = (float*)d_out;
  float* out_mc = out_mt + (size_t)NE;

  ushort* W = (ushort*)d_ws;
  ushort* qzh = W;
  ushort* qzl = qzh + NE;
  ushort* qzT = qzl + NE;
  ushort* wh  = qzT + NE;
  ushort* wl  = wh + 1048576;
  ushort* quh = wl + 1048576;
  ushort* qul = quh + NE;
  ushort* qvh = qul + NE;
  ushort* qvl = qvh + NE;
  float* qcu = out_mt;
  float* qcv = out_mc;

  hipLaunchKernelGGL(prep_qz, dim3(32, 64), dim3(256), 0, stream, qz, qzh, qzl, qzT);
  hipLaunchKernelGGL(prep_w, dim3(1024), dim3(256), 0, stream, tu, tv, cu, cv, wh, wl);
  hipLaunchKernelGGL(proj_all, dim3(64, 8, 4), dim3(256), 0, stream,
                     qzh, qzl, wh, wl, quh, qul, qvh, qvl, qcu, qcv);
  hipLaunchKernelGGL(chan_attn_kernel, dim3(P_, B_), dim3(64), 0, stream,
                     qcu, qcv, qz, out_mc);
  hipLaunchKernelGGL(time_attn_v10, dim3(64, 32), dim3(256), 0, stream,
                     quh, qul, qvh, qvl, qzT, out_mt);
}